// Round 3
// baseline (14372.134 us; speedup 1.0000x reference)
//
#include <hip/hip_runtime.h>
#include <hip/hip_bf16.h>

// Problem constants (match reference)
#define N_ENT   100000
#define N_REL   200
#define DIM     256
#define DHALF   128
#define E_FULL  1600000
#define E_BATCH 200000
#define BN_EPS  1e-5f

// ---------------------------------------------------------------------------
// GEMM: Y[row, c] = sum_k X[row,k] * W[k,c], one row per block, 256 threads
// (thread c owns output column c). W is [K, 256] row-major -> W[k*256+c] is
// coalesced/broadcast and L2-resident (<=256KB).
// ---------------------------------------------------------------------------
template <int K>
__global__ void gemm_rowblock(const float* __restrict__ X,
                              const float* __restrict__ W,
                              float* __restrict__ Y) {
    __shared__ float xs[K];
    const int row = blockIdx.x;
    const int c = threadIdx.x;
    for (int k = c; k < K; k += 256) xs[k] = X[(long)row * K + k];
    __syncthreads();
    float acc = 0.f;
#pragma unroll 8
    for (int k = 0; k < K; ++k) acc += xs[k] * W[k * 256 + c];
    Y[(long)row * 256 + c] = acc;
}

// ---------------------------------------------------------------------------
// Edge scatter: agg[t[e], :] += r_weight[rel[e]] * H[s[e], :]
// 64 lanes per edge, 4 columns (float4 load) per lane -> 4 atomics.
// ---------------------------------------------------------------------------
__global__ void scatter_edges(const float* __restrict__ H,
                              const int* __restrict__ src,
                              const int* __restrict__ rel,
                              const int* __restrict__ tgt,
                              const float* __restrict__ rw,
                              float* __restrict__ agg) {
    const long gid = (long)blockIdx.x * blockDim.x + threadIdx.x;
    const int lane = (int)(gid & 63);
    const long e = gid >> 6;
    if (e >= E_FULL) return;
    const int s = src[e];
    const int t = tgt[e];
    const float w = rw[rel[e]];
    const int c0 = lane * 4;
    const float4 hv = *reinterpret_cast<const float4*>(H + (long)s * DIM + c0);
    float* ag = agg + (long)t * DIM + c0;
    atomicAdd(ag + 0, w * hv.x);
    atomicAdd(ag + 1, w * hv.y);
    atomicAdd(ag + 2, w * hv.z);
    atomicAdd(ag + 3, w * hv.w);
}

// ---------------------------------------------------------------------------
// BN column statistics: per-column sum and sum-of-squares over N rows.
// Each block handles ROWS rows; thread d owns column d (coalesced reads).
// ---------------------------------------------------------------------------
#define BN_ROWS 256
__global__ void bn_stats(const float* __restrict__ A,
                         float* __restrict__ sum,
                         float* __restrict__ sumsq) {
    const int d = threadIdx.x;
    const long row0 = (long)blockIdx.x * BN_ROWS;
    float s = 0.f, ss = 0.f;
    for (int r = 0; r < BN_ROWS; ++r) {
        const long row = row0 + r;
        if (row >= N_ENT) break;
        const float v = A[row * DIM + d];
        s += v;
        ss += v * v;
    }
    atomicAdd(&sum[d], s);
    atomicAdd(&sumsq[d], ss);
}

// ---------------------------------------------------------------------------
// BN apply + tanh. Note: the GCN bias (per-column constant) cancels exactly
// under batch-norm's mean subtraction, so it is intentionally omitted.
// Biased variance (ddof=0) to match torch BatchNorm1d training stats.
// ---------------------------------------------------------------------------
__global__ void bn_tanh(const float* __restrict__ A,
                        const float* __restrict__ sum,
                        const float* __restrict__ sumsq,
                        const float* __restrict__ gamma,
                        const float* __restrict__ beta,
                        float* __restrict__ X) {
    const float invN = 1.0f / (float)N_ENT;
    const long total = (long)N_ENT * DIM;
    long i = (long)blockIdx.x * blockDim.x + threadIdx.x;
    const long stride = (long)gridDim.x * blockDim.x;
    for (; i < total; i += stride) {
        const int d = (int)(i & (DIM - 1));
        const float mu = sum[d] * invN;
        const float var = sumsq[d] * invN - mu * mu;
        const float v = (A[i] - mu) * rsqrtf(var + BN_EPS) * gamma[d] + beta[d];
        X[i] = tanhf(v);
    }
}

// ---------------------------------------------------------------------------
// Output gather: out[0,e,:] = X[idx0[e],:]; out[1,e,:] = X[idx1[e],:]
// 64 lanes per edge, float4 per lane.
// ---------------------------------------------------------------------------
__global__ void gather_out(const float* __restrict__ X,
                           const int* __restrict__ idx0,
                           const int* __restrict__ idx1,
                           float* __restrict__ out) {
    const long gid = (long)blockIdx.x * blockDim.x + threadIdx.x;
    const int lane = (int)(gid & 63);
    const long e = gid >> 6;
    if (e >= E_BATCH) return;
    const int c0 = lane * 4;
    const float4 a = *reinterpret_cast<const float4*>(X + (long)idx0[e] * DIM + c0);
    const float4 b = *reinterpret_cast<const float4*>(X + (long)idx1[e] * DIM + c0);
    *reinterpret_cast<float4*>(out + (long)e * DIM + c0) = a;
    *reinterpret_cast<float4*>(out + (long)E_BATCH * DIM + (long)e * DIM + c0) = b;
}

extern "C" void kernel_launch(void* const* d_in, const int* in_sizes, int n_in,
                              void* d_out, int out_size, void* d_ws, size_t ws_size,
                              hipStream_t stream) {
    const int*   edge_index = (const int*)d_in[0];     // [2, E_BATCH]
    const float* edge_attr  = (const float*)d_in[1];   // [E_BATCH, N_REL]
    const int*   edge_data  = (const int*)d_in[2];     // [3, E_FULL]
    const float* entity_emb = (const float*)d_in[3];   // [N_ENT, 128]
    const float* r_weight   = (const float*)d_in[4];   // [N_REL, 1]
    const float* gc1_w      = (const float*)d_in[5];   // [128, 256]
    // gc1_b (d_in[6]) and gc2_b (d_in[8]) cancel under BN -- unused.
    const float* gc2_w      = (const float*)d_in[7];   // [256, 256]
    const float* r_emb_w    = (const float*)d_in[9];   // [N_REL, 256]
    const float* bn3_g      = (const float*)d_in[10];
    const float* bn3_b      = (const float*)d_in[11];
    const float* bn4_g      = (const float*)d_in[12];
    const float* bn4_b      = (const float*)d_in[13];
    float* out = (float*)d_out;

    const int* e_src = edge_data;                // [E_FULL]
    const int* e_rel = edge_data + E_FULL;
    const int* e_tgt = edge_data + 2 * E_FULL;
    const int* idx0 = edge_index;                // [E_BATCH]
    const int* idx1 = edge_index + E_BATCH;

    // Workspace layout: two 102.4MB node-feature buffers + BN stats.
    const size_t BUF = (size_t)N_ENT * DIM * sizeof(float);  // 102,400,000 B
    char* ws = (char*)d_ws;
    float* bufA  = (float*)ws;              // h1 -> x1 -> agg2
    float* bufB  = (float*)(ws + BUF);      // agg1 -> h2 -> x2
    float* stats = (float*)(ws + 2 * BUF);  // sum1, sumsq1, sum2, sumsq2
    float* sum1 = stats, *sumsq1 = stats + 256, *sum2 = stats + 512, *sumsq2 = stats + 768;

    const int scatterBlocks = (int)(((long)E_FULL * 64) / 256);    // 400000
    const int gatherBlocks  = (int)(((long)E_BATCH * 64) / 256);   // 50000
    const int statBlocks    = (N_ENT + BN_ROWS - 1) / BN_ROWS;     // 391

    // Zero BN stats
    hipMemsetAsync(stats, 0, 4 * 256 * sizeof(float), stream);

    // Layer 1: h1 = entity_emb @ gc1_w  (bufA)
    gemm_rowblock<DHALF><<<N_ENT, 256, 0, stream>>>(entity_emb, gc1_w, bufA);

    // agg1 (bufB) = scatter(h1)
    hipMemsetAsync(bufB, 0, BUF, stream);
    scatter_edges<<<scatterBlocks, 256, 0, stream>>>(bufA, e_src, e_rel, e_tgt, r_weight, bufB);

    // x1 (bufA) = tanh(BN3(agg1))
    bn_stats<<<statBlocks, 256, 0, stream>>>(bufB, sum1, sumsq1);
    bn_tanh<<<2048, 256, 0, stream>>>(bufB, sum1, sumsq1, bn3_g, bn3_b, bufA);

    // Layer 2: h2 (bufB) = x1 @ gc2_w
    gemm_rowblock<DIM><<<N_ENT, 256, 0, stream>>>(bufA, gc2_w, bufB);

    // agg2 (bufA) = scatter(h2)
    hipMemsetAsync(bufA, 0, BUF, stream);
    scatter_edges<<<scatterBlocks, 256, 0, stream>>>(bufB, e_src, e_rel, e_tgt, r_weight, bufA);

    // x2 (bufB) = tanh(BN4(agg2))
    bn_stats<<<statBlocks, 256, 0, stream>>>(bufA, sum2, sumsq2);
    bn_tanh<<<2048, 256, 0, stream>>>(bufA, sum2, sumsq2, bn4_g, bn4_b, bufB);

    // Outputs
    gather_out<<<gatherBlocks, 256, 0, stream>>>(bufB, idx0, idx1, out);
    gemm_rowblock<N_REL><<<E_BATCH, 256, 0, stream>>>(edge_attr, r_emb_w, out + (long)2 * E_BATCH * DIM);
}